// Round 6
// baseline (259.173 us; speedup 1.0000x reference)
//
#include <hip/hip_runtime.h>
#include <cstdint>

#define KDIM 128
#define BATCH 131072
#define NBLK 512           // persistent blocks: 2/CU, all co-resident
#define ITERS 4            // BATCH / (NBLK * 64 rows per block-tile)

typedef __attribute__((ext_vector_type(8))) short short8x;          // MFMA A/B frag
typedef __attribute__((ext_vector_type(4))) float float4x;          // MFMA C/D frag
typedef __attribute__((ext_vector_type(4))) unsigned int uint4x;

// pack two fp32 -> bf16x2 dword, round-half-up (1 add per elem + 1 v_perm)
__device__ __forceinline__ unsigned int pk_bf16(float a, float b) {
    unsigned int ua = __float_as_uint(a) + 0x8000u;
    unsigned int ub = __float_as_uint(b) + 0x8000u;
    return __builtin_amdgcn_perm(ub, ua, 0x07060302u);  // {hi16(b), hi16(a)}
}

__device__ __forceinline__ unsigned short f2bf(float f) {   // RNE, prep kernel only
    unsigned int u = __float_as_uint(f);
    u += 0x7FFFu + ((u >> 16) & 1u);
    return (unsigned short)(u >> 16);
}

// clamped Pade tanh: err<=0.025 abs; y-sensitivity 0.05 -> <1.3e-3 in y. No transcendental.
__device__ __forceinline__ float tanh_pade(float v) {
    float z  = fminf(fmaxf(v, -4.0f), 4.0f);
    float z2 = z * z;
    float num = z * (27.0f + z2);
    float den = fmaf(z2, 9.0f, 27.0f);
    return num * __frcp_rn(den);
}

// direct-to-LDS 16B async copy: LDS dest = (wave-uniform base) + lane*16
__device__ __forceinline__ void gload_lds16(const void* g, void* l) {
    __builtin_amdgcn_global_load_lds(
        (const __attribute__((address_space(1))) void*)g,
        (__attribute__((address_space(3))) void*)l, 16, 0, 0);
}

// Stage one 16-row x-tile (8KB) into an LDS buffer: 8 x 1KB fully-coalesced loads.
// Source is slot-swizzled per lane (slot s ^ (row&7)); LDS dest stays linear, so the
// landed layout is the bank-swizzled one all LDS readers use.
__device__ __forceinline__ void stage_tile(const float* __restrict__ x, float* ldsbuf,
                                           int row0, int lane) {
    #pragma unroll
    for (int c = 0; c < 8; ++c) {
        int r = c * 2 + (lane >> 5);
        int s = (lane & 31) ^ (r & 7);
        gload_lds16(x + (size_t)(row0 + r) * KDIM + s * 4, ldsbuf + c * 256);
    }
}

// Repack W[k][n] fp32 -> fragment-lane-major bf16: coalesced reads, scattered writes.
// Main kernel reads Wf[((nt*4+ks)*64 + lane)*8 + j] = W[ks*32+(lane>>4)*8+j][nt*16+(lane&15)]
__global__ void prep_weights(const float* __restrict__ W1, const float* __restrict__ W2,
                             unsigned short* __restrict__ W1f, unsigned short* __restrict__ W2f) {
    int idx = blockIdx.x * 256 + threadIdx.x;   // 0..16383, coalesced read W[idx]
    int k = idx >> 7, n = idx & 127;
    int ks = k >> 5, j = k & 7;
    int lane = ((k >> 3) & 3) * 16 + (n & 15);
    int nt = n >> 4;
    int dst = ((nt * 4 + ks) * 64 + lane) * 8 + j;
    W1f[dst] = f2bf(W1[idx]);
    W2f[dst] = f2bf(W2[idx]);
}

// Persistent, wave-private, barrier-free, software-pipelined:
//   stage(t+1) issued before compute(t); single counted vmcnt(8) per iteration
//   (8 newest = previous tile's y stores; stage(t) is >=72 deep in the in-order
//   vmcnt queue => complete; stage(t+1) stays in flight under the whole compute).
__global__ __launch_bounds__(256, 2) void koopman_main(
        const float* __restrict__ x, const float* __restrict__ b1,
        const float* __restrict__ b2, const unsigned short* __restrict__ W1f,
        const unsigned short* __restrict__ W2f, float* __restrict__ y) {
    __shared__ __align__(16) float XY[4][2][2048];   // per wave: 2 x 8KB dbuf = 64KB/block

    const int tid  = threadIdx.x;
    const int lane = tid & 63;
    const int wave = tid >> 6;
    const int l15  = lane & 15;
    const int quad = lane >> 4;
    const int Lx   = l15 + ((lane & 16) << 1);   // shuffle src: l15 + 32a
    const bool bhi = (lane & 32) != 0;

    // prologue: prefetch W1 ks=0 frags + stage tile 0 (both drain at it=0's vmcnt(0))
    short8x wf[8];
    #pragma unroll
    for (int nt = 0; nt < 8; ++nt)
        wf[nt] = *(const short8x*)&W1f[((nt * 4 + 0) * 64 + lane) * 8];
    stage_tile(x, &XY[wave][0][0], blockIdx.x * 64 + wave * 16, lane);

    #pragma unroll 2
    for (int it = 0; it < ITERS; ++it) {
        float* Xw = &XY[wave][it & 1][0];
        const int row0 = (blockIdx.x + it * NBLK) * 64 + wave * 16;

        // ---- wait for THIS tile's stage only; keep next stage + stores in flight ----
        if (it == 0) { asm volatile("s_waitcnt vmcnt(0)" ::: "memory"); }
        else         { asm volatile("s_waitcnt vmcnt(8)" ::: "memory"); }

        // ---- issue next tile's stage immediately: covered by this tile's compute ----
        if (it + 1 < ITERS)
            stage_tile(x, &XY[wave][(it + 1) & 1][0],
                       (blockIdx.x + (it + 1) * NBLK) * 64 + wave * 16, lane);

        // ---- pack bf16 B-frags (X^T): lane reads row l15, slots ks*8+quad*2, +1 ----
        short8x xf[4];
        #pragma unroll
        for (int ks = 0; ks < 4; ++ks) {
            int t0 = ks * 8 + quad * 2;
            float4 v0 = *(const float4*)&Xw[l15 * 128 + (((t0    ) ^ (l15 & 7)) << 2)];
            float4 v1 = *(const float4*)&Xw[l15 * 128 + (((t0 + 1) ^ (l15 & 7)) << 2)];
            uint4x u;
            u[0] = pk_bf16(v0.x, v0.y);
            u[1] = pk_bf16(v0.z, v0.w);
            u[2] = pk_bf16(v1.x, v1.y);
            u[3] = pk_bf16(v1.z, v1.w);
            xf[ks] = __builtin_bit_cast(short8x, u);
        }

        // ---- matmul 1: rolling W-frag buffer; ks=3 prefetches W2 ks0 under tanh ----
        float4x acc[8];
        #pragma unroll
        for (int nt = 0; nt < 8; ++nt) acc[nt] = (float4x){0.f, 0.f, 0.f, 0.f};
        #pragma unroll
        for (int ks = 0; ks < 4; ++ks) {
            short8x wn[8];
            #pragma unroll
            for (int nt = 0; nt < 8; ++nt) {
                const unsigned short* src = (ks < 3)
                    ? &W1f[((nt * 4 + ks + 1) * 64 + lane) * 8]
                    : &W2f[((nt * 4 + 0) * 64 + lane) * 8];
                wn[nt] = *(const short8x*)src;
            }
            #pragma unroll
            for (int nt = 0; nt < 8; ++nt)
                acc[nt] = __builtin_amdgcn_mfma_f32_16x16x32_bf16(wf[nt], xf[ks], acc[nt], 0, 0, 0);
            #pragma unroll
            for (int nt = 0; nt < 8; ++nt) wf[nt] = wn[nt];
        }

        // ---- bias + tanh -> packed bf16 pairs in registers:
        //      lane(l15,q) holds d[nt] = H[l15][16nt+4q + {0,1 | 2,3}] ----
        uint2 d[8];
        #pragma unroll
        for (int nt = 0; nt < 8; ++nt) {
            float4 bb = *(const float4*)&b1[nt * 16 + quad * 4];
            float4x v = acc[nt];
            float t0 = tanh_pade(v[0] + bb.x);
            float t1 = tanh_pade(v[1] + bb.y);
            float t2 = tanh_pade(v[2] + bb.z);
            float t3 = tanh_pade(v[3] + bb.w);
            d[nt].x = pk_bf16(t0, t1);
            d[nt].y = pk_bf16(t2, t3);
        }

        // ---- matmul 2: B-frags via quad shuffles; ks=3 prefetches NEXT iter's W1 ks0.
        //      Target lane(a=bit4,b=bit5) dword w <- lane l15+16*(w>>1)+32a, d[2ks+b], half w&1.
        float4x acc2[8];
        #pragma unroll
        for (int nt = 0; nt < 8; ++nt) acc2[nt] = (float4x){0.f, 0.f, 0.f, 0.f};
        #pragma unroll
        for (int ks = 0; ks < 4; ++ks) {
            short8x wn[8];
            #pragma unroll
            for (int nt = 0; nt < 8; ++nt) {
                const unsigned short* src = (ks < 3)
                    ? &W2f[((nt * 4 + ks + 1) * 64 + lane) * 8]
                    : &W1f[((nt * 4 + 0) * 64 + lane) * 8];   // wraps to next iteration
                wn[nt] = *(const short8x*)src;
            }
            uint2 lo = d[2 * ks], hi = d[2 * ks + 1];
            unsigned s0 = (unsigned)__shfl((int)lo.x, Lx);
            unsigned s1 = (unsigned)__shfl((int)lo.y, Lx);
            unsigned s2 = (unsigned)__shfl((int)lo.x, Lx + 16);
            unsigned s3 = (unsigned)__shfl((int)lo.y, Lx + 16);
            unsigned t0 = (unsigned)__shfl((int)hi.x, Lx);
            unsigned t1 = (unsigned)__shfl((int)hi.y, Lx);
            unsigned t2 = (unsigned)__shfl((int)hi.x, Lx + 16);
            unsigned t3 = (unsigned)__shfl((int)hi.y, Lx + 16);
            uint4x u;
            u[0] = bhi ? t0 : s0;
            u[1] = bhi ? t1 : s1;
            u[2] = bhi ? t2 : s2;
            u[3] = bhi ? t3 : s3;
            short8x hf = __builtin_bit_cast(short8x, u);
            #pragma unroll
            for (int nt = 0; nt < 8; ++nt)
                acc2[nt] = __builtin_amdgcn_mfma_f32_16x16x32_bf16(wf[nt], hf, acc2[nt], 0, 0, 0);
            #pragma unroll
            for (int nt = 0; nt < 8; ++nt) wf[nt] = wn[nt];
        }

        // ---- fused epilogue, in-place in LDS: read x slot, compute, write y to slot ----
        #pragma unroll
        for (int nt = 0; nt < 8; ++nt) {
            float4 bv = *(const float4*)&b2[nt * 16 + quad * 4];
            int off = l15 * 128 + (((nt * 4 + quad) ^ (l15 & 7)) << 2);
            float4 xv = *(const float4*)&Xw[off];
            float4x v = acc2[nt];
            float4 out;
            {
                float tm = 0.01f * (v[0] + bv.x);
                float tw = 0.01f * (v[1] + bv.y);
                float tm2 = tm * tm, tw2 = tw * tw;
                float ex = fmaf(tm2, fmaf(tm, 0.16666667f, 0.5f), 1.0f + tm);
                float s  = tw * fmaf(tw2, -0.16666667f, 1.0f);
                float c  = fmaf(tw2, -0.5f, 1.0f);
                out.x = ex * fmaf(c, xv.x, -s * xv.y);
                out.y = ex * fmaf(s, xv.x,  c * xv.y);
            }
            {
                float tm = 0.01f * (v[2] + bv.z);
                float tw = 0.01f * (v[3] + bv.w);
                float tm2 = tm * tm, tw2 = tw * tw;
                float ex = fmaf(tm2, fmaf(tm, 0.16666667f, 0.5f), 1.0f + tm);
                float s  = tw * fmaf(tw2, -0.16666667f, 1.0f);
                float c  = fmaf(tw2, -0.5f, 1.0f);
                out.z = ex * fmaf(c, xv.z, -s * xv.w);
                out.w = ex * fmaf(s, xv.z,  c * xv.w);
            }
            *(float4*)&Xw[off] = out;
        }

        // ---- y store: linear LDS read; global dst carries inverse swizzle; nontemporal
        //      (y never read again -> don't evict x from L3). 8 stores = the "8" in vmcnt(8).
        //      NOTE: builtin requires a clang ext-vector pointee, not HIP's float4 class.
        #pragma unroll
        for (int c = 0; c < 8; ++c) {
            int r  = c * 2 + (lane >> 5);
            int sp = (lane & 31) ^ (r & 7);
            float4x v = *(const float4x*)&Xw[c * 256 + lane * 4];
            __builtin_nontemporal_store(v, (float4x*)(y + (size_t)(row0 + r) * KDIM + sp * 4));
        }
    }
}

extern "C" void kernel_launch(void* const* d_in, const int* in_sizes, int n_in,
                              void* d_out, int out_size, void* d_ws, size_t ws_size,
                              hipStream_t stream) {
    const float* x  = (const float*)d_in[0];
    const float* W1 = (const float*)d_in[1];
    const float* b1 = (const float*)d_in[2];
    const float* W2 = (const float*)d_in[3];
    const float* b2 = (const float*)d_in[4];
    float* y = (float*)d_out;

    unsigned short* W1f = (unsigned short*)d_ws;
    unsigned short* W2f = W1f + 128 * 128;

    prep_weights<<<64, 256, 0, stream>>>(W1, W2, W1f, W2f);
    koopman_main<<<NBLK, 256, 0, stream>>>(x, b1, b2, W1f, W2f, y);
}

// Round 7
// 255.581 us; speedup vs baseline: 1.0141x; 1.0141x over previous
//
#include <hip/hip_runtime.h>
#include <cstdint>

#define KDIM 128
#define BATCH 131072
#define NBLK 512           // persistent blocks: 2/CU, all co-resident
#define ITERS 4            // BATCH / (NBLK * 64 rows per block-tile)

typedef __attribute__((ext_vector_type(8))) short short8x;          // MFMA A/B frag
typedef __attribute__((ext_vector_type(4))) float float4x;          // MFMA C/D frag
typedef __attribute__((ext_vector_type(4))) unsigned int uint4x;

// pack two fp32 -> bf16x2 dword, round-half-up (1 add per elem + 1 v_perm)
__device__ __forceinline__ unsigned int pk_bf16(float a, float b) {
    unsigned int ua = __float_as_uint(a) + 0x8000u;
    unsigned int ub = __float_as_uint(b) + 0x8000u;
    return __builtin_amdgcn_perm(ub, ua, 0x07060302u);  // {hi16(b), hi16(a)}
}

__device__ __forceinline__ unsigned short f2bf(float f) {   // RNE, prep kernel only
    unsigned int u = __float_as_uint(f);
    u += 0x7FFFu + ((u >> 16) & 1u);
    return (unsigned short)(u >> 16);
}

// clamped Pade tanh: err<=0.025 abs; y-sensitivity 0.05 -> <1.3e-3 in y. No transcendental.
__device__ __forceinline__ float tanh_pade(float v) {
    float z  = fminf(fmaxf(v, -4.0f), 4.0f);
    float z2 = z * z;
    float num = z * (27.0f + z2);
    float den = fmaf(z2, 9.0f, 27.0f);
    return num * __frcp_rn(den);
}

// direct-to-LDS 16B async copy: LDS dest = (wave-uniform base) + lane*16
__device__ __forceinline__ void gload_lds16(const void* g, void* l) {
    __builtin_amdgcn_global_load_lds(
        (const __attribute__((address_space(1))) void*)g,
        (__attribute__((address_space(3))) void*)l, 16, 0, 0);
}

// Stage one 16-row x-tile (8KB) into an LDS buffer: 8 x 1KB fully-coalesced loads.
// Source is slot-swizzled per lane (slot s ^ (row&7)); LDS dest stays linear, so the
// landed layout is the bank-swizzled one all LDS readers use.
__device__ __forceinline__ void stage_tile(const float* __restrict__ x, float* ldsbuf,
                                           int row0, int lane) {
    #pragma unroll
    for (int c = 0; c < 8; ++c) {
        int r = c * 2 + (lane >> 5);
        int s = (lane & 31) ^ (r & 7);
        gload_lds16(x + (size_t)(row0 + r) * KDIM + s * 4, ldsbuf + c * 256);
    }
}

// Repack W[k][n] fp32 -> fragment-lane-major bf16: coalesced reads, scattered writes.
// Main kernel reads Wf[((nt*4+ks)*64 + lane)*8 + j] = W[ks*32+(lane>>4)*8+j][nt*16+(lane&15)]
__global__ void prep_weights(const float* __restrict__ W1, const float* __restrict__ W2,
                             unsigned short* __restrict__ W1f, unsigned short* __restrict__ W2f) {
    int idx = blockIdx.x * 256 + threadIdx.x;   // 0..16383, coalesced read W[idx]
    int k = idx >> 7, n = idx & 127;
    int ks = k >> 5, j = k & 7;
    int lane = ((k >> 3) & 3) * 16 + (n & 15);
    int nt = n >> 4;
    int dst = ((nt * 4 + ks) * 64 + lane) * 8 + j;
    W1f[dst] = f2bf(W1[idx]);
    W2f[dst] = f2bf(W2[idx]);
}

// Persistent, wave-private, barrier-free, software-pipelined:
//   stage(t+1) issued before compute(t); single counted vmcnt(8) per iteration
//   (8 newest = previous tile's y stores; stage(t) is >=72 deep in the in-order
//   vmcnt queue => complete; stage(t+1) stays in flight under the whole compute).
// y stores go through the NORMAL cached path: L2 write-combining reassembles the
// lane-permuted 16B stores into full lines (round-6 lesson: nt + permuted dst = 5x RMW).
__global__ __launch_bounds__(256, 2) void koopman_main(
        const float* __restrict__ x, const float* __restrict__ b1,
        const float* __restrict__ b2, const unsigned short* __restrict__ W1f,
        const unsigned short* __restrict__ W2f, float* __restrict__ y) {
    __shared__ __align__(16) float XY[4][2][2048];   // per wave: 2 x 8KB dbuf = 64KB/block

    const int tid  = threadIdx.x;
    const int lane = tid & 63;
    const int wave = tid >> 6;
    const int l15  = lane & 15;
    const int quad = lane >> 4;
    const int Lx   = l15 + ((lane & 16) << 1);   // shuffle src: l15 + 32a
    const bool bhi = (lane & 32) != 0;

    // prologue: prefetch W1 ks=0 frags + stage tile 0 (both drain at it=0's vmcnt(0))
    short8x wf[8];
    #pragma unroll
    for (int nt = 0; nt < 8; ++nt)
        wf[nt] = *(const short8x*)&W1f[((nt * 4 + 0) * 64 + lane) * 8];
    stage_tile(x, &XY[wave][0][0], blockIdx.x * 64 + wave * 16, lane);

    #pragma unroll 2
    for (int it = 0; it < ITERS; ++it) {
        float* Xw = &XY[wave][it & 1][0];
        const int row0 = (blockIdx.x + it * NBLK) * 64 + wave * 16;

        // ---- wait for THIS tile's stage only; keep next stage + stores in flight ----
        if (it == 0) { asm volatile("s_waitcnt vmcnt(0)" ::: "memory"); }
        else         { asm volatile("s_waitcnt vmcnt(8)" ::: "memory"); }

        // ---- issue next tile's stage immediately: covered by this tile's compute ----
        if (it + 1 < ITERS)
            stage_tile(x, &XY[wave][(it + 1) & 1][0],
                       (blockIdx.x + (it + 1) * NBLK) * 64 + wave * 16, lane);

        // ---- pack bf16 B-frags (X^T): lane reads row l15, slots ks*8+quad*2, +1 ----
        short8x xf[4];
        #pragma unroll
        for (int ks = 0; ks < 4; ++ks) {
            int t0 = ks * 8 + quad * 2;
            float4 v0 = *(const float4*)&Xw[l15 * 128 + (((t0    ) ^ (l15 & 7)) << 2)];
            float4 v1 = *(const float4*)&Xw[l15 * 128 + (((t0 + 1) ^ (l15 & 7)) << 2)];
            uint4x u;
            u[0] = pk_bf16(v0.x, v0.y);
            u[1] = pk_bf16(v0.z, v0.w);
            u[2] = pk_bf16(v1.x, v1.y);
            u[3] = pk_bf16(v1.z, v1.w);
            xf[ks] = __builtin_bit_cast(short8x, u);
        }

        // ---- matmul 1: rolling W-frag buffer; ks=3 prefetches W2 ks0 under tanh ----
        float4x acc[8];
        #pragma unroll
        for (int nt = 0; nt < 8; ++nt) acc[nt] = (float4x){0.f, 0.f, 0.f, 0.f};
        #pragma unroll
        for (int ks = 0; ks < 4; ++ks) {
            short8x wn[8];
            #pragma unroll
            for (int nt = 0; nt < 8; ++nt) {
                const unsigned short* src = (ks < 3)
                    ? &W1f[((nt * 4 + ks + 1) * 64 + lane) * 8]
                    : &W2f[((nt * 4 + 0) * 64 + lane) * 8];
                wn[nt] = *(const short8x*)src;
            }
            #pragma unroll
            for (int nt = 0; nt < 8; ++nt)
                acc[nt] = __builtin_amdgcn_mfma_f32_16x16x32_bf16(wf[nt], xf[ks], acc[nt], 0, 0, 0);
            #pragma unroll
            for (int nt = 0; nt < 8; ++nt) wf[nt] = wn[nt];
        }

        // ---- bias + tanh -> packed bf16 pairs in registers:
        //      lane(l15,q) holds d[nt] = H[l15][16nt+4q + {0,1 | 2,3}] ----
        uint2 d[8];
        #pragma unroll
        for (int nt = 0; nt < 8; ++nt) {
            float4 bb = *(const float4*)&b1[nt * 16 + quad * 4];
            float4x v = acc[nt];
            float t0 = tanh_pade(v[0] + bb.x);
            float t1 = tanh_pade(v[1] + bb.y);
            float t2 = tanh_pade(v[2] + bb.z);
            float t3 = tanh_pade(v[3] + bb.w);
            d[nt].x = pk_bf16(t0, t1);
            d[nt].y = pk_bf16(t2, t3);
        }

        // ---- matmul 2: B-frags via quad shuffles; ks=3 prefetches NEXT iter's W1 ks0.
        //      Target lane(a=bit4,b=bit5) dword w <- lane l15+16*(w>>1)+32a, d[2ks+b], half w&1.
        float4x acc2[8];
        #pragma unroll
        for (int nt = 0; nt < 8; ++nt) acc2[nt] = (float4x){0.f, 0.f, 0.f, 0.f};
        #pragma unroll
        for (int ks = 0; ks < 4; ++ks) {
            short8x wn[8];
            #pragma unroll
            for (int nt = 0; nt < 8; ++nt) {
                const unsigned short* src = (ks < 3)
                    ? &W2f[((nt * 4 + ks + 1) * 64 + lane) * 8]
                    : &W1f[((nt * 4 + 0) * 64 + lane) * 8];   // wraps to next iteration
                wn[nt] = *(const short8x*)src;
            }
            uint2 lo = d[2 * ks], hi = d[2 * ks + 1];
            unsigned s0 = (unsigned)__shfl((int)lo.x, Lx);
            unsigned s1 = (unsigned)__shfl((int)lo.y, Lx);
            unsigned s2 = (unsigned)__shfl((int)lo.x, Lx + 16);
            unsigned s3 = (unsigned)__shfl((int)lo.y, Lx + 16);
            unsigned t0 = (unsigned)__shfl((int)hi.x, Lx);
            unsigned t1 = (unsigned)__shfl((int)hi.y, Lx);
            unsigned t2 = (unsigned)__shfl((int)hi.x, Lx + 16);
            unsigned t3 = (unsigned)__shfl((int)hi.y, Lx + 16);
            uint4x u;
            u[0] = bhi ? t0 : s0;
            u[1] = bhi ? t1 : s1;
            u[2] = bhi ? t2 : s2;
            u[3] = bhi ? t3 : s3;
            short8x hf = __builtin_bit_cast(short8x, u);
            #pragma unroll
            for (int nt = 0; nt < 8; ++nt)
                acc2[nt] = __builtin_amdgcn_mfma_f32_16x16x32_bf16(wf[nt], hf, acc2[nt], 0, 0, 0);
            #pragma unroll
            for (int nt = 0; nt < 8; ++nt) wf[nt] = wn[nt];
        }

        // ---- fused epilogue, in-place in LDS: read x slot, compute, write y to slot ----
        #pragma unroll
        for (int nt = 0; nt < 8; ++nt) {
            float4 bv = *(const float4*)&b2[nt * 16 + quad * 4];
            int off = l15 * 128 + (((nt * 4 + quad) ^ (l15 & 7)) << 2);
            float4 xv = *(const float4*)&Xw[off];
            float4x v = acc2[nt];
            float4 out;
            {
                float tm = 0.01f * (v[0] + bv.x);
                float tw = 0.01f * (v[1] + bv.y);
                float tm2 = tm * tm, tw2 = tw * tw;
                float ex = fmaf(tm2, fmaf(tm, 0.16666667f, 0.5f), 1.0f + tm);
                float s  = tw * fmaf(tw2, -0.16666667f, 1.0f);
                float c  = fmaf(tw2, -0.5f, 1.0f);
                out.x = ex * fmaf(c, xv.x, -s * xv.y);
                out.y = ex * fmaf(s, xv.x,  c * xv.y);
            }
            {
                float tm = 0.01f * (v[2] + bv.z);
                float tw = 0.01f * (v[3] + bv.w);
                float tm2 = tm * tm, tw2 = tw * tw;
                float ex = fmaf(tm2, fmaf(tm, 0.16666667f, 0.5f), 1.0f + tm);
                float s  = tw * fmaf(tw2, -0.16666667f, 1.0f);
                float c  = fmaf(tw2, -0.5f, 1.0f);
                out.z = ex * fmaf(c, xv.z, -s * xv.w);
                out.w = ex * fmaf(s, xv.z,  c * xv.w);
            }
            *(float4*)&Xw[off] = out;
        }

        // ---- y store: linear LDS read; global dst carries inverse swizzle; NORMAL
        //      cached stores (L2 reassembles permuted lanes into full lines).
        //      8 stores = the "8" in vmcnt(8).
        #pragma unroll
        for (int c = 0; c < 8; ++c) {
            int r  = c * 2 + (lane >> 5);
            int sp = (lane & 31) ^ (r & 7);
            float4x v = *(const float4x*)&Xw[c * 256 + lane * 4];
            *(float4x*)(y + (size_t)(row0 + r) * KDIM + sp * 4) = v;
        }
    }
}

extern "C" void kernel_launch(void* const* d_in, const int* in_sizes, int n_in,
                              void* d_out, int out_size, void* d_ws, size_t ws_size,
                              hipStream_t stream) {
    const float* x  = (const float*)d_in[0];
    const float* W1 = (const float*)d_in[1];
    const float* b1 = (const float*)d_in[2];
    const float* W2 = (const float*)d_in[3];
    const float* b2 = (const float*)d_in[4];
    float* y = (float*)d_out;

    unsigned short* W1f = (unsigned short*)d_ws;
    unsigned short* W2f = W1f + 128 * 128;

    prep_weights<<<64, 256, 0, stream>>>(W1, W2, W1f, W2f);
    koopman_main<<<NBLK, 256, 0, stream>>>(x, b1, b2, W1f, W2f, y);
}

// Round 8
// 146.135 us; speedup vs baseline: 1.7735x; 1.7489x over previous
//
#include <hip/hip_runtime.h>
#include <cstdint>

#define KDIM 128
#define BATCH 131072

typedef __attribute__((ext_vector_type(8))) short short8x;          // MFMA A/B frag
typedef __attribute__((ext_vector_type(4))) float float4x;          // MFMA C/D frag
typedef __attribute__((ext_vector_type(4))) unsigned int uint4x;

// pack two fp32 -> bf16x2 dword, round-half-up (1 add per elem + 1 v_perm)
__device__ __forceinline__ unsigned int pk_bf16(float a, float b) {
    unsigned int ua = __float_as_uint(a) + 0x8000u;
    unsigned int ub = __float_as_uint(b) + 0x8000u;
    return __builtin_amdgcn_perm(ub, ua, 0x07060302u);  // {hi16(b), hi16(a)}
}

__device__ __forceinline__ unsigned short f2bf(float f) {   // RNE, prep kernel only
    unsigned int u = __float_as_uint(f);
    u += 0x7FFFu + ((u >> 16) & 1u);
    return (unsigned short)(u >> 16);
}

// clamped Pade tanh: err<=0.025 abs; y-sensitivity 0.05 -> <1.3e-3 in y. No transcendental.
__device__ __forceinline__ float tanh_pade(float v) {
    float z  = fminf(fmaxf(v, -4.0f), 4.0f);
    float z2 = z * z;
    float num = z * (27.0f + z2);
    float den = fmaf(z2, 9.0f, 27.0f);
    return num * __frcp_rn(den);
}

// direct-to-LDS 16B async copy: LDS dest = (wave-uniform base) + lane*16
__device__ __forceinline__ void gload_lds16(const void* g, void* l) {
    __builtin_amdgcn_global_load_lds(
        (const __attribute__((address_space(1))) void*)g,
        (__attribute__((address_space(3))) void*)l, 16, 0, 0);
}

// Repack W[k][n] fp32 -> fragment-lane-major bf16: coalesced reads, scattered writes.
// Main kernel reads Wf[((nt*4+ks)*64 + lane)*8 + j] = W[ks*32+(lane>>4)*8+j][nt*16+(lane&15)]
__global__ void prep_weights(const float* __restrict__ W1, const float* __restrict__ W2,
                             unsigned short* __restrict__ W1f, unsigned short* __restrict__ W2f) {
    int idx = blockIdx.x * 256 + threadIdx.x;   // 0..16383, coalesced read W[idx]
    int k = idx >> 7, n = idx & 127;
    int ks = k >> 5, j = k & 7;
    int lane = ((k >> 3) & 3) * 16 + (n & 15);
    int nt = n >> 4;
    int dst = ((nt * 4 + ks) * 64 + lane) * 8 + j;
    W1f[dst] = f2bf(W1[idx]);
    W2f[dst] = f2bf(W2[idx]);
}

// Non-persistent, wave-private, barrier-free. M=16 rows/wave, 4 blocks/CU (TLP path:
// 16 resident waves/CU desynchronize so CU-level memory issue stays continuous).
//  - x staged via global_load_lds (8 x 1KB coalesced), source slot-swizzled
//  - H matmul1->matmul2 handoff fully in-register via quad shuffles (no H LDS)
//  - y written back in-place into the x LDS region, stored as 8 x 1KB contiguous
__global__ __launch_bounds__(256, 4) void koopman_main(
        const float* __restrict__ x, const float* __restrict__ b1,
        const float* __restrict__ b2, const unsigned short* __restrict__ W1f,
        const unsigned short* __restrict__ W2f, float* __restrict__ y) {
    __shared__ __align__(16) float XY[4][2048];   // 8KB/wave x/y stage = 32KB/block

    const int tid  = threadIdx.x;
    const int lane = tid & 63;
    const int wave = tid >> 6;
    const int l15  = lane & 15;
    const int quad = lane >> 4;
    const int Lx   = l15 + ((lane & 16) << 1);   // shuffle src: l15 + 32a
    const bool bhi = (lane & 32) != 0;
    const int row0 = blockIdx.x * 64 + wave * 16;

    float* Xw = XY[wave];

    // ---- phase 1: stage 16 rows x 512B of x, fully coalesced, all 8 loads in flight.
    //      Source is slot-swizzled per lane; LDS dest stays linear (HW: base + lane*16).
    #pragma unroll
    for (int c = 0; c < 8; ++c) {
        int r = c * 2 + (lane >> 5);
        int s = (lane & 31) ^ (r & 7);
        gload_lds16(x + (size_t)(row0 + r) * KDIM + s * 4, &Xw[c * 256]);
    }
    asm volatile("s_waitcnt vmcnt(0)" ::: "memory");

    // ---- phase 2: build bf16 B-frags (X^T): lane reads row l15, slots ks*8+quad*2, +1 ----
    short8x xf[4];
    #pragma unroll
    for (int ks = 0; ks < 4; ++ks) {
        int t0 = ks * 8 + quad * 2;
        float4 v0 = *(const float4*)&Xw[l15 * 128 + (((t0    ) ^ (l15 & 7)) << 2)];
        float4 v1 = *(const float4*)&Xw[l15 * 128 + (((t0 + 1) ^ (l15 & 7)) << 2)];
        uint4x u;
        u[0] = pk_bf16(v0.x, v0.y);
        u[1] = pk_bf16(v0.z, v0.w);
        u[2] = pk_bf16(v1.x, v1.y);
        u[3] = pk_bf16(v1.z, v1.w);
        xf[ks] = __builtin_bit_cast(short8x, u);
    }

    // ---- matmul 1: D[col][row] = W1^T @ X^T ; W frags are coalesced 1KB loads ----
    float4x acc[8];
    #pragma unroll
    for (int nt = 0; nt < 8; ++nt) acc[nt] = (float4x){0.f, 0.f, 0.f, 0.f};
    #pragma unroll
    for (int ks = 0; ks < 4; ++ks) {
        #pragma unroll
        for (int nt = 0; nt < 8; ++nt) {
            short8x w = *(const short8x*)&W1f[((nt * 4 + ks) * 64 + lane) * 8];
            acc[nt] = __builtin_amdgcn_mfma_f32_16x16x32_bf16(w, xf[ks], acc[nt], 0, 0, 0);
        }
    }

    // ---- bias + tanh -> packed bf16 pairs in registers:
    //      lane(l15,q) holds d[nt] = H[l15][16nt+4q + {0,1 | 2,3}] ----
    uint2 d[8];
    #pragma unroll
    for (int nt = 0; nt < 8; ++nt) {
        float4 bb = *(const float4*)&b1[nt * 16 + quad * 4];
        float4x v = acc[nt];
        float t0 = tanh_pade(v[0] + bb.x);
        float t1 = tanh_pade(v[1] + bb.y);
        float t2 = tanh_pade(v[2] + bb.z);
        float t3 = tanh_pade(v[3] + bb.w);
        d[nt].x = pk_bf16(t0, t1);
        d[nt].y = pk_bf16(t2, t3);
    }

    // ---- matmul 2: B-frags built in-register via quad shuffles (verified round 3).
    //      Target lane(a=bit4,b=bit5) dword w <- lane l15+16*(w>>1)+32a, d[2ks+b], half w&1.
    float4x acc2[8];
    #pragma unroll
    for (int nt = 0; nt < 8; ++nt) acc2[nt] = (float4x){0.f, 0.f, 0.f, 0.f};
    #pragma unroll
    for (int ks = 0; ks < 4; ++ks) {
        uint2 lo = d[2 * ks], hi = d[2 * ks + 1];
        unsigned s0 = (unsigned)__shfl((int)lo.x, Lx);
        unsigned s1 = (unsigned)__shfl((int)lo.y, Lx);
        unsigned s2 = (unsigned)__shfl((int)lo.x, Lx + 16);
        unsigned s3 = (unsigned)__shfl((int)lo.y, Lx + 16);
        unsigned t0 = (unsigned)__shfl((int)hi.x, Lx);
        unsigned t1 = (unsigned)__shfl((int)hi.y, Lx);
        unsigned t2 = (unsigned)__shfl((int)hi.x, Lx + 16);
        unsigned t3 = (unsigned)__shfl((int)hi.y, Lx + 16);
        uint4x u;
        u[0] = bhi ? t0 : s0;
        u[1] = bhi ? t1 : s1;
        u[2] = bhi ? t2 : s2;
        u[3] = bhi ? t3 : s3;
        short8x hf = __builtin_bit_cast(short8x, u);
        #pragma unroll
        for (int nt = 0; nt < 8; ++nt) {
            short8x w = *(const short8x*)&W2f[((nt * 4 + ks) * 64 + lane) * 8];
            acc2[nt] = __builtin_amdgcn_mfma_f32_16x16x32_bf16(w, hf, acc2[nt], 0, 0, 0);
        }
    }

    // ---- fused epilogue, in-place in LDS: read x slot, compute, write y to same slot ----
    #pragma unroll
    for (int nt = 0; nt < 8; ++nt) {
        float4 bv = *(const float4*)&b2[nt * 16 + quad * 4];
        int off = l15 * 128 + (((nt * 4 + quad) ^ (l15 & 7)) << 2);
        float4 xv = *(const float4*)&Xw[off];
        float4x v = acc2[nt];
        float4 out;
        {
            float tm = 0.01f * (v[0] + bv.x);
            float tw = 0.01f * (v[1] + bv.y);
            float tm2 = tm * tm, tw2 = tw * tw;
            float ex = fmaf(tm2, fmaf(tm, 0.16666667f, 0.5f), 1.0f + tm);
            float s  = tw * fmaf(tw2, -0.16666667f, 1.0f);
            float c  = fmaf(tw2, -0.5f, 1.0f);
            out.x = ex * fmaf(c, xv.x, -s * xv.y);
            out.y = ex * fmaf(s, xv.x,  c * xv.y);
        }
        {
            float tm = 0.01f * (v[2] + bv.z);
            float tw = 0.01f * (v[3] + bv.w);
            float tm2 = tm * tm, tw2 = tw * tw;
            float ex = fmaf(tm2, fmaf(tm, 0.16666667f, 0.5f), 1.0f + tm);
            float s  = tw * fmaf(tw2, -0.16666667f, 1.0f);
            float c  = fmaf(tw2, -0.5f, 1.0f);
            out.z = ex * fmaf(c, xv.z, -s * xv.w);
            out.w = ex * fmaf(s, xv.z,  c * xv.w);
        }
        *(float4*)&Xw[off] = out;
    }

    // ---- y store: linear LDS read (conflict-free); global dst carries inverse swizzle;
    //      plain cached stores (L2 write-combining reassembles permuted lanes) ----
    #pragma unroll
    for (int c = 0; c < 8; ++c) {
        int r  = c * 2 + (lane >> 5);
        int sp = (lane & 31) ^ (r & 7);
        float4 v = *(const float4*)&Xw[c * 256 + lane * 4];
        float* dst = y + (size_t)(row0 + r) * KDIM + sp * 4;
        *(float4*)dst = v;
    }
}

extern "C" void kernel_launch(void* const* d_in, const int* in_sizes, int n_in,
                              void* d_out, int out_size, void* d_ws, size_t ws_size,
                              hipStream_t stream) {
    const float* x  = (const float*)d_in[0];
    const float* W1 = (const float*)d_in[1];
    const float* b1 = (const float*)d_in[2];
    const float* W2 = (const float*)d_in[3];
    const float* b2 = (const float*)d_in[4];
    float* y = (float*)d_out;

    unsigned short* W1f = (unsigned short*)d_ws;
    unsigned short* W2f = W1f + 128 * 128;

    prep_weights<<<64, 256, 0, stream>>>(W1, W2, W1f, W2f);
    koopman_main<<<BATCH / 64, 256, 0, stream>>>(x, b1, b2, W1f, W2f, y);
}